// Round 12
// baseline (45.841 us; speedup 1.0000x reference)
//
#include <hip/hip_runtime.h>
#include <math.h>

#define NB   64
#define D    256
#define HW   25
#define TRI  32896         // 256*257/2
#define FSTR 260           // padded p-row stride of full-batch transposed LDS

// e-subtile 4x4: acc[r][q] += |a_r+b_q| - |a_r-b_q| over p
__device__ __forceinline__ void comp44(const float* __restrict__ fs, int ib, int jb,
                                       int tx, int ty, float a[4][4]) {
#pragma unroll
    for (int r = 0; r < 4; ++r)
#pragma unroll
        for (int q = 0; q < 4; ++q) a[r][q] = 0.f;
#pragma unroll 5
    for (int p = 0; p < HW; ++p) {
        float4 av = *reinterpret_cast<const float4*>(&fs[p * FSTR + ib + ty * 4]);
        float4 bv = *reinterpret_cast<const float4*>(&fs[p * FSTR + jb + tx * 4]);
        float a4[4] = {av.x, av.y, av.z, av.w};
        float b4[4] = {bv.x, bv.y, bv.z, bv.w};
#pragma unroll
        for (int r = 0; r < 4; ++r)
#pragma unroll
            for (int q = 0; q < 4; ++q)
                a[r][q] += fabsf(a4[r] + b4[q]) - fabsf(a4[r] - b4[q]);
    }
}

__device__ __forceinline__ void store44(float* __restrict__ ob, const float* __restrict__ rsld,
                                        const float a[4][4], int ib, int jb, int tx, int ty,
                                        bool diag, float sc) {
    const float inv = 1.0f / 256.0f;
#pragma unroll
    for (int r = 0; r < 4; ++r) {
        const int i = ib + ty * 4 + r;
        const int off = (i * (513 - i)) >> 1;
        const float ri = rsld[i];
#pragma unroll
        for (int q = 0; q < 4; ++q) {
            const int j = jb + tx * 4 + q;
            if (!diag || j >= i)
                ob[off + (j - i)] = sc * (a[r][q] - (ri + rsld[j]) * inv);
        }
    }
}

// ---------------------------------------------------------------------------
// One block per batch (64 blocks x 1024 thr = 16 waves).  Single-node graph
// (R9 calibration: dur == kernel time).  Stage f[b] transposed once; 4 groups
// of 256 threads (16tx x 16ty, 4x4/thread) process the 10 triu band-tiles in
// 3 balanced rounds:
//   r0: (0,0)(0,1)(0,2)(0,3)   r1: (1,1)(1,2)(1,3)(2,2)
//   r2: (2,3) j-halves -> g0,g1 ; (3,3) j-halves -> g2,g3   (64x32, 2x4/thr)
// Diag tiles computed FULL so i-partials are complete row sums.  Row-sum
// partials: i-side reduced intra-wave via shfl_xor -> islot; j-side (transpose
// contributions) per-wave shfl + redj LDS.  acc stays in registers across the
// reduction; phase C writes the final centered value once.  No e in memory,
// no cross-block traffic, no atomics.
// ---------------------------------------------------------------------------
__global__ __launch_bounds__(1024) void fused_batch(const float* __restrict__ feat,
                                                    const float* __restrict__ temp,
                                                    float* __restrict__ out) {
    __shared__ __align__(16) float fs[HW * FSTR];   // 26 KB
    __shared__ float islot[4][4][64];               // i-partials per band/slot
    __shared__ float redj[3][4][4][64];             // j-partials [round][group][wave][col]
    __shared__ float rs[D];                         // full row sums

    const int tid  = threadIdx.x;
    const int b    = blockIdx.x;
    const int g    = tid >> 8;        // group 0..3 (256 thr each)
    const int gt   = tid & 255;
    const int lane = tid & 63;
    const int wv   = gt >> 6;         // wave within group
    const int tx   = gt & 15;
    const int ty   = gt >> 4;
    const int tx8  = gt & 7;
    const int ty32 = gt >> 3;

    const float* fb = feat + (size_t)b * D * HW;
    for (int idx = tid; idx < D * HW; idx += 1024) {
        const int r = idx / HW;
        const int p = idx - r * HW;
        fs[p * FSTR + r] = fb[idx];
    }
    __syncthreads();

    // round-1 tile per group: g0->(1,1) g1->(1,2) g2->(1,3) g3->(2,2)
    const int bi1 = (g == 3) ? 2 : 1;
    const int bj1 = (g == 3) ? 2 : (g + 1);
    const int ib0 = 0,         jb0 = g * 64;
    const int ib1 = bi1 * 64,  jb1 = bj1 * 64;
    const int ib2 = (g < 2) ? 128 : 192;          // t8=(2,3) / t9=(3,3)
    const int jb2 = 192 + (g & 1) * 32;           // j-half
    const bool dg0 = (g == 0);
    const bool dg1 = (g == 0) || (g == 3);
    const bool dg2 = (g >= 2);

    float acc0[4][4], acc1[4][4], acc2[2][4];

    // ---- round 0 ----
    comp44(fs, ib0, jb0, tx, ty, acc0);
    {
        float pi[4];
#pragma unroll
        for (int r = 0; r < 4; ++r)
            pi[r] = acc0[r][0] + acc0[r][1] + acc0[r][2] + acc0[r][3];
#pragma unroll
        for (int m = 1; m < 16; m <<= 1)
#pragma unroll
            for (int r = 0; r < 4; ++r) pi[r] += __shfl_xor(pi[r], m, 64);
        if ((lane & 15) == 0)
#pragma unroll
            for (int r = 0; r < 4; ++r) islot[0][g][ty * 4 + r] = pi[r];
    }
    if (!dg0) {
        float pj[4];
#pragma unroll
        for (int q = 0; q < 4; ++q)
            pj[q] = acc0[0][q] + acc0[1][q] + acc0[2][q] + acc0[3][q];
#pragma unroll
        for (int q = 0; q < 4; ++q) {
            pj[q] += __shfl_xor(pj[q], 16, 64);
            pj[q] += __shfl_xor(pj[q], 32, 64);
        }
        if (lane < 16)
#pragma unroll
            for (int q = 0; q < 4; ++q) redj[0][g][wv][lane * 4 + q] = pj[q];
    }

    // ---- round 1 ----
    comp44(fs, ib1, jb1, tx, ty, acc1);
    {
        const int sb = (g == 3) ? 2 : 1;
        const int si = (g == 3) ? 0 : g;
        float pi[4];
#pragma unroll
        for (int r = 0; r < 4; ++r)
            pi[r] = acc1[r][0] + acc1[r][1] + acc1[r][2] + acc1[r][3];
#pragma unroll
        for (int m = 1; m < 16; m <<= 1)
#pragma unroll
            for (int r = 0; r < 4; ++r) pi[r] += __shfl_xor(pi[r], m, 64);
        if ((lane & 15) == 0)
#pragma unroll
            for (int r = 0; r < 4; ++r) islot[sb][si][ty * 4 + r] = pi[r];
    }
    if (g == 1 || g == 2) {   // t5=(1,2)->redj[1][1], t6=(1,3)->redj[1][2]
        float pj[4];
#pragma unroll
        for (int q = 0; q < 4; ++q)
            pj[q] = acc1[0][q] + acc1[1][q] + acc1[2][q] + acc1[3][q];
#pragma unroll
        for (int q = 0; q < 4; ++q) {
            pj[q] += __shfl_xor(pj[q], 16, 64);
            pj[q] += __shfl_xor(pj[q], 32, 64);
        }
        if (lane < 16)
#pragma unroll
            for (int q = 0; q < 4; ++q) redj[1][g][wv][lane * 4 + q] = pj[q];
    }

    // ---- round 2: half tiles 64x32, thread = (tx8, ty32), 2x4/thread ----
    {
#pragma unroll
        for (int r = 0; r < 2; ++r)
#pragma unroll
            for (int q = 0; q < 4; ++q) acc2[r][q] = 0.f;
#pragma unroll 5
        for (int p = 0; p < HW; ++p) {
            float2 av = *reinterpret_cast<const float2*>(&fs[p * FSTR + ib2 + ty32 * 2]);
            float4 bv = *reinterpret_cast<const float4*>(&fs[p * FSTR + jb2 + tx8 * 4]);
            float a2[2] = {av.x, av.y};
            float b4[4] = {bv.x, bv.y, bv.z, bv.w};
#pragma unroll
            for (int r = 0; r < 2; ++r)
#pragma unroll
                for (int q = 0; q < 4; ++q)
                    acc2[r][q] += fabsf(a2[r] + b4[q]) - fabsf(a2[r] - b4[q]);
        }
        const int sb = (g < 2) ? 2 : 3;
        const int si = (g < 2) ? (1 + g) : (g - 2);
        float pi[2];
#pragma unroll
        for (int r = 0; r < 2; ++r)
            pi[r] = acc2[r][0] + acc2[r][1] + acc2[r][2] + acc2[r][3];
#pragma unroll
        for (int m = 1; m < 8; m <<= 1)
#pragma unroll
            for (int r = 0; r < 2; ++r) pi[r] += __shfl_xor(pi[r], m, 64);
        if ((lane & 7) == 0)
#pragma unroll
            for (int r = 0; r < 2; ++r) islot[sb][si][ty32 * 2 + r] = pi[r];
        if (g < 2) {            // t8 j-halves -> redj[2][g], cols 0..31
            float pj[4];
#pragma unroll
            for (int q = 0; q < 4; ++q) pj[q] = acc2[0][q] + acc2[1][q];
#pragma unroll
            for (int q = 0; q < 4; ++q) {
                pj[q] += __shfl_xor(pj[q], 8, 64);
                pj[q] += __shfl_xor(pj[q], 16, 64);
                pj[q] += __shfl_xor(pj[q], 32, 64);
            }
            if (lane < 8)
#pragma unroll
                for (int q = 0; q < 4; ++q) redj[2][g][wv][lane * 4 + q] = pj[q];
        }
    }
    __syncthreads();

    // ---- phase B: full row sums ----
    if (tid < D) {
        const int w = tid >> 6, c = tid & 63;
        const int nis[4] = {4, 3, 3, 2};
        float s = 0.f;
        for (int k = 0; k < nis[w]; ++k) s += islot[w][k][c];
        if (w == 1) {
#pragma unroll
            for (int v = 0; v < 4; ++v) s += redj[0][1][v][c];
        } else if (w == 2) {
#pragma unroll
            for (int v = 0; v < 4; ++v) s += redj[0][2][v][c] + redj[1][1][v][c];
        } else if (w == 3) {
#pragma unroll
            for (int v = 0; v < 4; ++v) s += redj[0][3][v][c] + redj[1][2][v][c];
            if (c < 32) {
#pragma unroll
                for (int v = 0; v < 4; ++v) s += redj[2][0][v][c];
            } else {
#pragma unroll
                for (int v = 0; v < 4; ++v) s += redj[2][1][v][c - 32];
            }
        }
        rs[tid] = s;
    }
    __syncthreads();

    // ---- phase C: center + store (from registers) ----
    const float sc = 0.5f * expf(temp[0]);
    float* ob = out + (size_t)b * TRI;
    store44(ob, rs, acc0, ib0, jb0, tx, ty, dg0, sc);
    store44(ob, rs, acc1, ib1, jb1, tx, ty, dg1, sc);
    {
        const float inv = 1.0f / 256.0f;
#pragma unroll
        for (int r = 0; r < 2; ++r) {
            const int i = ib2 + ty32 * 2 + r;
            const int off = (i * (513 - i)) >> 1;
            const float ri = rs[i];
#pragma unroll
            for (int q = 0; q < 4; ++q) {
                const int j = jb2 + tx8 * 4 + q;
                if (!dg2 || j >= i)
                    ob[off + (j - i)] = sc * (acc2[r][q] - (ri + rs[j]) * inv);
            }
        }
    }
}

extern "C" void kernel_launch(void* const* d_in, const int* in_sizes, int n_in,
                              void* d_out, int out_size, void* d_ws, size_t ws_size,
                              hipStream_t stream) {
    const float* feat = (const float*)d_in[0];
    const float* temp = (const float*)d_in[1];
    float* out = (float*)d_out;

    fused_batch<<<NB, 1024, 0, stream>>>(feat, temp, out);
}